// Round 1
// baseline (2942.549 us; speedup 1.0000x reference)
//
#include <hip/hip_runtime.h>

// SmoothGCN: out = ((x@Wn + bn) + (segsum(x[src]*w, dst)@We + be)) @ Wm + bm
// Refactor: y = x@We; h = x@Wn + bn + be; h[dst] += w_e * y[src]; out = h@Wm + bm
// (LeakyReLU slope=1.0 == identity.)

constexpr int N_NODES  = 50000;
constexpr int N_EDGES  = 1600000;
constexpr int IN_FEAT  = 256;
constexpr int HID      = 128;
constexpr int OUT_FEAT = 256;

static __device__ __forceinline__ void fma4(float4& a, float s, const float4& b) {
    a.x += s * b.x; a.y += s * b.y; a.z += s * b.z; a.w += s * b.w;
}

// K1: h = x@Wn + (bn+be), y = x@We.  Block: 256 thr = 32 colgroups(4 cols) x 8
// rowgroups(8 nodes); 64 nodes/block. LDS x-tile 64x256 f32 = 64KB.
// Wave map: lanes 0..31 = cg0..31 rg r, lanes 32..63 = rg r+1 -> LDS reads are
// 2 distinct rows (stride 256 floats, same banks) = 2-way conflict = free (m136).
__global__ __launch_bounds__(256) void k1_dual_matmul(
    const float* __restrict__ x, const float* __restrict__ Wn,
    const float* __restrict__ bn, const float* __restrict__ We,
    const float* __restrict__ be, float* __restrict__ h, float* __restrict__ y)
{
    __shared__ float xs[64][IN_FEAT];  // 65536 B
    const int t = threadIdx.x;
    const int node0 = blockIdx.x * 64;

    // cooperative x-tile load: 4096 float4s, 16 per thread, coalesced
    const float4* xg = (const float4*)x;
    #pragma unroll
    for (int i = 0; i < 16; ++i) {
        int f4 = t + i * 256;              // tile-local float4 index
        int node = node0 + (f4 >> 6);      // 64 float4 per row
        float4 v = make_float4(0.f, 0.f, 0.f, 0.f);
        if (node < N_NODES) v = xg[(size_t)node * 64 + (f4 & 63)];
        ((float4*)xs)[f4] = v;
    }
    __syncthreads();

    const int cg = t & 31;
    const int rg = t >> 5;
    const int j0 = cg * 4;
    const float* xrow = &xs[rg * 8][0];

    float4 acc_h[8], acc_y[8];
    #pragma unroll
    for (int n = 0; n < 8; ++n) {
        acc_h[n] = make_float4(0.f, 0.f, 0.f, 0.f);
        acc_y[n] = make_float4(0.f, 0.f, 0.f, 0.f);
    }

    for (int k = 0; k < IN_FEAT; k += 4) {
        float4 wn[4], we[4];
        #pragma unroll
        for (int kk = 0; kk < 4; ++kk) {
            wn[kk] = *(const float4*)&Wn[(size_t)(k + kk) * HID + j0];
            we[kk] = *(const float4*)&We[(size_t)(k + kk) * HID + j0];
        }
        #pragma unroll
        for (int n = 0; n < 8; ++n) {
            float4 xv = *(const float4*)&xrow[n * IN_FEAT + k];  // ds_read_b128
            fma4(acc_h[n], xv.x, wn[0]); fma4(acc_y[n], xv.x, we[0]);
            fma4(acc_h[n], xv.y, wn[1]); fma4(acc_y[n], xv.y, we[1]);
            fma4(acc_h[n], xv.z, wn[2]); fma4(acc_y[n], xv.z, we[2]);
            fma4(acc_h[n], xv.w, wn[3]); fma4(acc_y[n], xv.w, we[3]);
        }
    }

    float4 b1 = *(const float4*)&bn[j0];
    float4 b2 = *(const float4*)&be[j0];
    float4 bias = make_float4(b1.x + b2.x, b1.y + b2.y, b1.z + b2.z, b1.w + b2.w);

    #pragma unroll
    for (int n = 0; n < 8; ++n) {
        int node = node0 + rg * 8 + n;
        if (node < N_NODES) {
            float4 hv = acc_h[n];
            hv.x += bias.x; hv.y += bias.y; hv.z += bias.z; hv.w += bias.w;
            *(float4*)&h[(size_t)node * HID + j0] = hv;
            *(float4*)&y[(size_t)node * HID + j0] = acc_y[n];
        }
    }
}

// K2: h[dst[e]] += w[e] * y[src[e]].  32 threads/edge, 4 feats/thread.
__global__ __launch_bounds__(256) void k2_scatter(
    const float* __restrict__ y, const float* __restrict__ w,
    const int* __restrict__ src, const int* __restrict__ dst,
    float* __restrict__ h)
{
    int id = blockIdx.x * 256 + threadIdx.x;
    int e  = id >> 5;
    int fg = id & 31;
    if (e >= N_EDGES) return;
    int s = src[e];
    int d = dst[e];
    float wt = w[e];
    float4 yv = *(const float4*)&y[(size_t)s * HID + fg * 4];
    float* hp = &h[(size_t)d * HID + fg * 4];
    unsafeAtomicAdd(hp + 0, wt * yv.x);   // hardware global_atomic_add_f32
    unsafeAtomicAdd(hp + 1, wt * yv.y);
    unsafeAtomicAdd(hp + 2, wt * yv.z);
    unsafeAtomicAdd(hp + 3, wt * yv.w);
}

// K3: out = h@Wm + bm. Block: 256 thr = 64 colgroups(4 cols) x 4 rowgroups
// (16 nodes); 64 nodes/block. LDS h-tile 64x128 f32 = 32KB. Wave = one
// rowgroup -> all 64 lanes read the same LDS address (broadcast, free).
__global__ __launch_bounds__(256) void k3_matmul(
    const float* __restrict__ h, const float* __restrict__ Wm,
    const float* __restrict__ bm, float* __restrict__ out)
{
    __shared__ float hs[64][HID];  // 32768 B
    const int t = threadIdx.x;
    const int node0 = blockIdx.x * 64;

    const float4* hg = (const float4*)h;
    #pragma unroll
    for (int i = 0; i < 8; ++i) {
        int f4 = t + i * 256;              // 2048 float4s in tile
        int node = node0 + (f4 >> 5);      // 32 float4 per row
        float4 v = make_float4(0.f, 0.f, 0.f, 0.f);
        if (node < N_NODES) v = hg[(size_t)node * 32 + (f4 & 31)];
        ((float4*)hs)[f4] = v;
    }
    __syncthreads();

    const int cg = t & 63;
    const int rg = t >> 6;
    const int j0 = cg * 4;
    const float* hrow = &hs[rg * 16][0];

    float4 acc[16];
    #pragma unroll
    for (int n = 0; n < 16; ++n) acc[n] = make_float4(0.f, 0.f, 0.f, 0.f);

    for (int k = 0; k < HID; k += 4) {
        float4 wm[4];
        #pragma unroll
        for (int kk = 0; kk < 4; ++kk)
            wm[kk] = *(const float4*)&Wm[(size_t)(k + kk) * OUT_FEAT + j0];
        #pragma unroll
        for (int n = 0; n < 16; ++n) {
            float4 xv = *(const float4*)&hrow[n * HID + k];
            fma4(acc[n], xv.x, wm[0]);
            fma4(acc[n], xv.y, wm[1]);
            fma4(acc[n], xv.z, wm[2]);
            fma4(acc[n], xv.w, wm[3]);
        }
    }

    float4 bias = *(const float4*)&bm[j0];
    #pragma unroll
    for (int n = 0; n < 16; ++n) {
        int node = node0 + rg * 16 + n;
        if (node < N_NODES) {
            float4 ov = acc[n];
            ov.x += bias.x; ov.y += bias.y; ov.z += bias.z; ov.w += bias.w;
            *(float4*)&out[(size_t)node * OUT_FEAT + j0] = ov;
        }
    }
}

extern "C" void kernel_launch(void* const* d_in, const int* in_sizes, int n_in,
                              void* d_out, int out_size, void* d_ws, size_t ws_size,
                              hipStream_t stream) {
    const float* x   = (const float*)d_in[0];
    const float* w   = (const float*)d_in[1];
    const int*   src = (const int*)d_in[2];
    const int*   dst = (const int*)d_in[3];
    const float* Wn  = (const float*)d_in[4];
    const float* bn  = (const float*)d_in[5];
    const float* We  = (const float*)d_in[6];
    const float* be  = (const float*)d_in[7];
    const float* Wm  = (const float*)d_in[8];
    const float* bm  = (const float*)d_in[9];
    float* out = (float*)d_out;

    float* y = (float*)d_ws;                      // [N_NODES, HID]
    float* h = y + (size_t)N_NODES * HID;         // [N_NODES, HID]

    dim3 blk(256);
    int grid_mm = (N_NODES + 63) / 64;            // 782
    k1_dual_matmul<<<grid_mm, blk, 0, stream>>>(x, Wn, bn, We, be, h, y);
    int grid_sc = (N_EDGES * 32) / 256;           // 200000
    k2_scatter<<<grid_sc, blk, 0, stream>>>(y, w, src, dst, h);
    k3_matmul<<<grid_mm, blk, 0, stream>>>(h, Wm, bm, out);
}

// Round 2
// 570.074 us; speedup vs baseline: 5.1617x; 5.1617x over previous
//
#include <hip/hip_runtime.h>

// SmoothGCN: out = ((x@Wn + bn) + (segsum(x[src]*w, dst)@We + be)) @ Wm + bm
// Refactor: y = x@We; h = x@Wn + bn + be; h[dst] += w_e*y[src]; out = h@Wm + bm
// R2: replace fp-atomic scatter (3.28 GB HBM write-through, 2674 us) with
// device-built CSR + per-node pull gather (no fp atomics, h written once).

constexpr int N_NODES  = 50000;
constexpr int N_EDGES  = 1600000;
constexpr int IN_FEAT  = 256;
constexpr int HID      = 128;
constexpr int OUT_FEAT = 256;

static __device__ __forceinline__ void fma4(float4& a, float s, const float4& b) {
    a.x += s * b.x; a.y += s * b.y; a.z += s * b.z; a.w += s * b.w;
}

// ---------------- K1: h = x@Wn + (bn+be), y = x@We ----------------
// 256 thr = 32 colgroups(4 cols) x 8 rowgroups(8 nodes); 64 nodes/block.
__global__ __launch_bounds__(256) void k1_dual_matmul(
    const float* __restrict__ x, const float* __restrict__ Wn,
    const float* __restrict__ bn, const float* __restrict__ We,
    const float* __restrict__ be, float* __restrict__ h, float* __restrict__ y)
{
    __shared__ float xs[64][IN_FEAT];  // 64 KB
    const int t = threadIdx.x;
    const int node0 = blockIdx.x * 64;

    const float4* xg = (const float4*)x;
    #pragma unroll
    for (int i = 0; i < 16; ++i) {
        int f4 = t + i * 256;
        int node = node0 + (f4 >> 6);
        float4 v = make_float4(0.f, 0.f, 0.f, 0.f);
        if (node < N_NODES) v = xg[(size_t)node * 64 + (f4 & 63)];
        ((float4*)xs)[f4] = v;
    }
    __syncthreads();

    const int cg = t & 31;
    const int rg = t >> 5;
    const int j0 = cg * 4;
    const float* xrow = &xs[rg * 8][0];

    float4 acc_h[8], acc_y[8];
    #pragma unroll
    for (int n = 0; n < 8; ++n) {
        acc_h[n] = make_float4(0.f, 0.f, 0.f, 0.f);
        acc_y[n] = make_float4(0.f, 0.f, 0.f, 0.f);
    }

    for (int k = 0; k < IN_FEAT; k += 4) {
        float4 wn[4], we[4];
        #pragma unroll
        for (int kk = 0; kk < 4; ++kk) {
            wn[kk] = *(const float4*)&Wn[(size_t)(k + kk) * HID + j0];
            we[kk] = *(const float4*)&We[(size_t)(k + kk) * HID + j0];
        }
        #pragma unroll
        for (int n = 0; n < 8; ++n) {
            float4 xv = *(const float4*)&xrow[n * IN_FEAT + k];
            fma4(acc_h[n], xv.x, wn[0]); fma4(acc_y[n], xv.x, we[0]);
            fma4(acc_h[n], xv.y, wn[1]); fma4(acc_y[n], xv.y, we[1]);
            fma4(acc_h[n], xv.z, wn[2]); fma4(acc_y[n], xv.z, we[2]);
            fma4(acc_h[n], xv.w, wn[3]); fma4(acc_y[n], xv.w, we[3]);
        }
    }

    float4 b1 = *(const float4*)&bn[j0];
    float4 b2 = *(const float4*)&be[j0];
    float4 bias = make_float4(b1.x + b2.x, b1.y + b2.y, b1.z + b2.z, b1.w + b2.w);

    #pragma unroll
    for (int n = 0; n < 8; ++n) {
        int node = node0 + rg * 8 + n;
        if (node < N_NODES) {
            float4 hv = acc_h[n];
            hv.x += bias.x; hv.y += bias.y; hv.z += bias.z; hv.w += bias.w;
            *(float4*)&h[(size_t)node * HID + j0] = hv;
            *(float4*)&y[(size_t)node * HID + j0] = acc_y[n];
        }
    }
}

// ---------------- CSR build ----------------
__global__ __launch_bounds__(256) void k_hist(const int* __restrict__ dst,
                                              int* __restrict__ deg) {
    int e = blockIdx.x * 256 + threadIdx.x;
    if (e < N_EDGES) atomicAdd(&deg[dst[e]], 1);  // no-return int atomic
}

// per-256-block inclusive scan -> exclusive partials (in-place over deg ok via
// separate output) + block sums
__global__ __launch_bounds__(256) void k_scan1(const int* __restrict__ deg,
                                               int* __restrict__ pexcl,
                                               int* __restrict__ bsum) {
    __shared__ int buf[256];
    int t = threadIdx.x;
    int i = blockIdx.x * 256 + t;
    int v = (i < N_NODES) ? deg[i] : 0;
    buf[t] = v; __syncthreads();
    #pragma unroll
    for (int off = 1; off < 256; off <<= 1) {
        int xx = (t >= off) ? buf[t - off] : 0;
        __syncthreads();
        buf[t] += xx;
        __syncthreads();
    }
    if (i < N_NODES) pexcl[i] = buf[t] - v;
    if (t == 255) bsum[blockIdx.x] = buf[255];
}

__global__ __launch_bounds__(256) void k_scan2(const int* __restrict__ bsum,
                                               int* __restrict__ boff, int nblk) {
    __shared__ int buf[256];
    int t = threadIdx.x;
    int v = (t < nblk) ? bsum[t] : 0;
    buf[t] = v; __syncthreads();
    #pragma unroll
    for (int off = 1; off < 256; off <<= 1) {
        int xx = (t >= off) ? buf[t - off] : 0;
        __syncthreads();
        buf[t] += xx;
        __syncthreads();
    }
    if (t < nblk) boff[t] = buf[t] - v;
}

__global__ __launch_bounds__(256) void k_scan3(const int* __restrict__ pexcl,
                                               const int* __restrict__ boff,
                                               int* __restrict__ rowptr,
                                               int* __restrict__ cur) {
    int i = blockIdx.x * 256 + threadIdx.x;
    if (i < N_NODES) {
        int r = pexcl[i] + boff[blockIdx.x];
        rowptr[i] = r;
        cur[i] = r;
    }
    if (i == 0) rowptr[N_NODES] = N_EDGES;
}

__global__ __launch_bounds__(256) void k_fill(const int* __restrict__ src,
                                              const int* __restrict__ dst,
                                              const float* __restrict__ w,
                                              int* __restrict__ cur,
                                              int2* __restrict__ epack) {
    int e = blockIdx.x * 256 + threadIdx.x;
    if (e < N_EDGES) {
        int d = dst[e];
        int pos = atomicAdd(&cur[d], 1);
        epack[pos] = make_int2(src[e], __float_as_int(w[e]));
    }
}

// ---------------- Gather: h[v] += sum_e w_e * y[src_e] ----------------
// One wave per node; lane owns float2 of the 128 features. Edge meta
// broadcast via __shfl; each edge = one 512B coalesced y-row read (L3-hot).
__global__ __launch_bounds__(256) void k_gather(const float* __restrict__ y,
                                                const int* __restrict__ rowptr,
                                                const int2* __restrict__ epack,
                                                float* __restrict__ h) {
    const int lane = threadIdx.x & 63;
    const int v = blockIdx.x * 4 + (threadIdx.x >> 6);
    const int beg = rowptr[v];
    const int end = rowptr[v + 1];
    const int f0 = lane * 2;

    float2 acc = *(const float2*)&h[(size_t)v * HID + f0];

    for (int base = beg; base < end; base += 64) {
        int idx = base + lane;
        int2 ep = make_int2(0, 0);
        if (idx < end) ep = epack[idx];
        int cnt = min(64, end - base);
        for (int j = 0; j < cnt; ++j) {
            int s = __shfl(ep.x, j, 64);
            float wt = __int_as_float(__shfl(ep.y, j, 64));
            float2 yv = *(const float2*)&y[(size_t)s * HID + f0];
            acc.x += wt * yv.x;
            acc.y += wt * yv.y;
        }
    }
    *(float2*)&h[(size_t)v * HID + f0] = acc;
}

// ---------------- K3: out = h@Wm + bm ----------------
__global__ __launch_bounds__(256) void k3_matmul(
    const float* __restrict__ h, const float* __restrict__ Wm,
    const float* __restrict__ bm, float* __restrict__ out)
{
    __shared__ float hs[64][HID];  // 32 KB
    const int t = threadIdx.x;
    const int node0 = blockIdx.x * 64;

    const float4* hg = (const float4*)h;
    #pragma unroll
    for (int i = 0; i < 8; ++i) {
        int f4 = t + i * 256;
        int node = node0 + (f4 >> 5);
        float4 v = make_float4(0.f, 0.f, 0.f, 0.f);
        if (node < N_NODES) v = hg[(size_t)node * 32 + (f4 & 31)];
        ((float4*)hs)[f4] = v;
    }
    __syncthreads();

    const int cg = t & 63;
    const int rg = t >> 6;
    const int j0 = cg * 4;
    const float* hrow = &hs[rg * 16][0];

    float4 acc[16];
    #pragma unroll
    for (int n = 0; n < 16; ++n) acc[n] = make_float4(0.f, 0.f, 0.f, 0.f);

    for (int k = 0; k < HID; k += 4) {
        float4 wm[4];
        #pragma unroll
        for (int kk = 0; kk < 4; ++kk)
            wm[kk] = *(const float4*)&Wm[(size_t)(k + kk) * OUT_FEAT + j0];
        #pragma unroll
        for (int n = 0; n < 16; ++n) {
            float4 xv = *(const float4*)&hrow[n * HID + k];
            fma4(acc[n], xv.x, wm[0]);
            fma4(acc[n], xv.y, wm[1]);
            fma4(acc[n], xv.z, wm[2]);
            fma4(acc[n], xv.w, wm[3]);
        }
    }

    float4 bias = *(const float4*)&bm[j0];
    #pragma unroll
    for (int n = 0; n < 16; ++n) {
        int node = node0 + rg * 16 + n;
        if (node < N_NODES) {
            float4 ov = acc[n];
            ov.x += bias.x; ov.y += bias.y; ov.z += bias.z; ov.w += bias.w;
            *(float4*)&out[(size_t)node * OUT_FEAT + j0] = ov;
        }
    }
}

extern "C" void kernel_launch(void* const* d_in, const int* in_sizes, int n_in,
                              void* d_out, int out_size, void* d_ws, size_t ws_size,
                              hipStream_t stream) {
    const float* x   = (const float*)d_in[0];
    const float* w   = (const float*)d_in[1];
    const int*   src = (const int*)d_in[2];
    const int*   dst = (const int*)d_in[3];
    const float* Wn  = (const float*)d_in[4];
    const float* bn  = (const float*)d_in[5];
    const float* We  = (const float*)d_in[6];
    const float* be  = (const float*)d_in[7];
    const float* Wm  = (const float*)d_in[8];
    const float* bm  = (const float*)d_in[9];
    float* out = (float*)d_out;

    // workspace layout (16B aligned chunks)
    char* p = (char*)d_ws;
    float* y      = (float*)p;                 p += (size_t)N_NODES * HID * 4;   // 25.6 MB
    float* h      = (float*)p;                 p += (size_t)N_NODES * HID * 4;   // 25.6 MB
    int2*  epack  = (int2*)p;                  p += (size_t)N_EDGES * 8;         // 12.8 MB
    int*   rowptr = (int*)p;                   p += (size_t)(N_NODES + 16) * 4;
    int*   cur    = (int*)p;                   p += (size_t)N_NODES * 4;
    int*   deg    = (int*)p;                   p += (size_t)N_NODES * 4;
    int*   pexcl  = (int*)p;                   p += (size_t)N_NODES * 4;
    int*   bsum   = (int*)p;                   p += 256 * 4;
    int*   boff   = (int*)p;                   p += 256 * 4;

    const int nblk_nodes = (N_NODES + 255) / 256;   // 196
    const int nblk_edges = (N_EDGES + 255) / 256;   // 6250
    dim3 blk(256);

    hipMemsetAsync(deg, 0, (size_t)N_NODES * 4, stream);
    k_hist <<<nblk_edges, blk, 0, stream>>>(dst, deg);
    k_scan1<<<nblk_nodes, blk, 0, stream>>>(deg, pexcl, bsum);
    k_scan2<<<1,          blk, 0, stream>>>(bsum, boff, nblk_nodes);
    k_scan3<<<nblk_nodes, blk, 0, stream>>>(pexcl, boff, rowptr, cur);
    k_fill <<<nblk_edges, blk, 0, stream>>>(src, dst, w, cur, epack);

    int grid_mm = (N_NODES + 63) / 64;              // 782
    k1_dual_matmul<<<grid_mm, blk, 0, stream>>>(x, Wn, bn, We, be, h, y);
    k_gather<<<N_NODES / 4, blk, 0, stream>>>(y, rowptr, epack, h);  // 12500
    k3_matmul<<<grid_mm, blk, 0, stream>>>(h, Wm, bm, out);
}

// Round 3
// 475.046 us; speedup vs baseline: 6.1942x; 1.2000x over previous
//
#include <hip/hip_runtime.h>

// SmoothGCN: out = ((x@Wn + bn) + (segsum(x[src]*w, dst)@We + be)) @ Wm + bm
// Refactor: y = x@We; h = x@Wn + bn + be; h[dst] += w_e*y[src]; out = h@Wm + bm
// R3: MFMA bf16 GEMMs for both matmuls (fp32 has no MFMA on CDNA4), bf16 y/h
// in the gather path. CSR build (hist+scan+fill) unchanged from R2.

constexpr int N_NODES  = 50000;
constexpr int N_EDGES  = 1600000;
constexpr int IN_FEAT  = 256;
constexpr int HID      = 128;
constexpr int OUT_FEAT = 256;

typedef __attribute__((ext_vector_type(8))) short bf16x8;
typedef __attribute__((ext_vector_type(4))) float f32x4;

static __device__ __forceinline__ unsigned short f2bf(float f) {
    unsigned u = __builtin_bit_cast(unsigned, f);
    u += 0x7FFF + ((u >> 16) & 1);          // round-to-nearest-even
    return (unsigned short)(u >> 16);
}

// ---------------- k0: transpose+convert weights to bf16 ----------------
// Wcat_t[n][k]: n<128 -> Wn[k][n]; n>=128 -> We[k][n-128].  Wmt[n][k] = Wm[k][n].
__global__ __launch_bounds__(256) void k0_convert(
    const float* __restrict__ Wn, const float* __restrict__ We,
    const float* __restrict__ Wm,
    unsigned short* __restrict__ Wcat_t, unsigned short* __restrict__ Wmt)
{
    int n = blockIdx.x;      // 0..255
    int k = threadIdx.x;     // 0..255
    float v = (n < HID) ? Wn[(size_t)k * HID + n] : We[(size_t)k * HID + (n - HID)];
    Wcat_t[(size_t)n * IN_FEAT + k] = f2bf(v);
    if (k < HID) Wmt[(size_t)n * HID + k] = f2bf(Wm[(size_t)k * OUT_FEAT + n]);
}

// ---------------- GEMM1: h0 = x@Wn + (bn+be)  (y-half: ybf = bf16(x@We)) ---
// M-tile 128, N-tile 128 (blockIdx.y selects Wn/We half), K=256 staged in 2
// halves of 128. 4 waves, each 64x64 via 4x4 grid of 16x16x32 bf16 MFMA.
__global__ __launch_bounds__(256) void gemm1(
    const float* __restrict__ x, const unsigned short* __restrict__ Wcat_t,
    const float* __restrict__ bn, const float* __restrict__ be,
    float* __restrict__ h0, unsigned short* __restrict__ ybf)
{
    __shared__ unsigned short As[128][128];  // 32 KB
    __shared__ unsigned short Bs[128][128];  // 32 KB
    const int t = threadIdx.x;
    const int m0 = blockIdx.x * 128;
    const int nhalf = blockIdx.y;            // 0 -> h0, 1 -> ybf
    const int n0r = nhalf * 128;             // row offset into Wcat_t

    const int wave = t >> 6, lane = t & 63;
    const int wm = wave & 1, wn = wave >> 1;
    const int la = lane & 15, kq = lane >> 4;

    f32x4 acc[4][4];
    const f32x4 zero = {0.f, 0.f, 0.f, 0.f};
    #pragma unroll
    for (int i = 0; i < 4; ++i)
        #pragma unroll
        for (int j = 0; j < 4; ++j) acc[i][j] = zero;

    const float4* xg = (const float4*)x;             // 64 f4 per x row
    const float4* bg = (const float4*)Wcat_t;        // 32 f4 per Wcat row

    for (int kh = 0; kh < 2; ++kh) {
        if (kh) __syncthreads();
        // A stage: x[m0..m0+127][kh*128..+128] fp32 -> bf16; 4096 float4s
        #pragma unroll
        for (int i = 0; i < 16; ++i) {
            int f4  = t + i * 256;
            int row = f4 >> 5;               // 32 f4 per LDS row
            int c4  = f4 & 31;
            int node = m0 + row;
            float4 v = make_float4(0.f, 0.f, 0.f, 0.f);
            if (node < N_NODES) v = xg[(size_t)node * 64 + kh * 32 + c4];
            ushort4 b;
            b.x = f2bf(v.x); b.y = f2bf(v.y); b.z = f2bf(v.z); b.w = f2bf(v.w);
            *(ushort4*)&As[row][c4 * 4] = b;
        }
        // B stage: Wcat_t[n0r..n0r+127][kh*128..+128] bf16 copy; 2048 float4s
        #pragma unroll
        for (int i = 0; i < 8; ++i) {
            int f4  = t + i * 256;
            int row = f4 >> 4;               // 16 f4 per LDS row
            int c4  = f4 & 15;
            ((float4*)&Bs[0][0])[f4] = bg[(size_t)(n0r + row) * 32 + kh * 16 + c4];
        }
        __syncthreads();

        #pragma unroll
        for (int ks = 0; ks < 4; ++ks) {
            int k = ks * 32 + kq * 8;
            bf16x8 a[4], b[4];
            #pragma unroll
            for (int i = 0; i < 4; ++i)
                a[i] = *(const bf16x8*)&As[wm * 64 + i * 16 + la][k];
            #pragma unroll
            for (int j = 0; j < 4; ++j)
                b[j] = *(const bf16x8*)&Bs[wn * 64 + j * 16 + la][k];
            #pragma unroll
            for (int i = 0; i < 4; ++i)
                #pragma unroll
                for (int j = 0; j < 4; ++j)
                    acc[i][j] = __builtin_amdgcn_mfma_f32_16x16x32_bf16(
                        a[i], b[j], acc[i][j], 0, 0, 0);
        }
    }

    // Epilogue. D mapping: col = la, row = kq*4 + r (m89-verified).
    float bias[4];
    if (nhalf == 0) {
        #pragma unroll
        for (int j = 0; j < 4; ++j) {
            int n = wn * 64 + j * 16 + la;
            bias[j] = bn[n] + be[n];
        }
    }
    #pragma unroll
    for (int i = 0; i < 4; ++i) {
        int mbase = m0 + wm * 64 + i * 16 + kq * 4;
        #pragma unroll
        for (int j = 0; j < 4; ++j) {
            int n = wn * 64 + j * 16 + la;
            #pragma unroll
            for (int r = 0; r < 4; ++r) {
                int m = mbase + r;
                if (m < N_NODES) {
                    if (nhalf == 0)
                        h0[(size_t)m * HID + n] = acc[i][j][r] + bias[j];
                    else
                        ybf[(size_t)m * HID + n] = f2bf(acc[i][j][r]);
                }
            }
        }
    }
}

// ---------------- CSR build (unchanged from R2) ----------------
__global__ __launch_bounds__(256) void k_hist(const int* __restrict__ dst,
                                              int* __restrict__ deg) {
    int e = blockIdx.x * 256 + threadIdx.x;
    if (e < N_EDGES) atomicAdd(&deg[dst[e]], 1);
}

__global__ __launch_bounds__(256) void k_scan1(const int* __restrict__ deg,
                                               int* __restrict__ pexcl,
                                               int* __restrict__ bsum) {
    __shared__ int buf[256];
    int t = threadIdx.x;
    int i = blockIdx.x * 256 + t;
    int v = (i < N_NODES) ? deg[i] : 0;
    buf[t] = v; __syncthreads();
    for (int off = 1; off < 256; off <<= 1) {
        int xx = (t >= off) ? buf[t - off] : 0;
        __syncthreads();
        buf[t] += xx;
        __syncthreads();
    }
    if (i < N_NODES) pexcl[i] = buf[t] - v;
    if (t == 255) bsum[blockIdx.x] = buf[255];
}

__global__ __launch_bounds__(256) void k_scan2(const int* __restrict__ bsum,
                                               int* __restrict__ boff, int nblk) {
    __shared__ int buf[256];
    int t = threadIdx.x;
    int v = (t < nblk) ? bsum[t] : 0;
    buf[t] = v; __syncthreads();
    for (int off = 1; off < 256; off <<= 1) {
        int xx = (t >= off) ? buf[t - off] : 0;
        __syncthreads();
        buf[t] += xx;
        __syncthreads();
    }
    if (t < nblk) boff[t] = buf[t] - v;
}

__global__ __launch_bounds__(256) void k_scan3(const int* __restrict__ pexcl,
                                               const int* __restrict__ boff,
                                               int* __restrict__ rowptr,
                                               int* __restrict__ cur) {
    int i = blockIdx.x * 256 + threadIdx.x;
    if (i < N_NODES) {
        int r = pexcl[i] + boff[blockIdx.x];
        rowptr[i] = r;
        cur[i] = r;
    }
    if (i == 0) rowptr[N_NODES] = N_EDGES;
}

__global__ __launch_bounds__(256) void k_fill(const int* __restrict__ src,
                                              const int* __restrict__ dst,
                                              const float* __restrict__ w,
                                              int* __restrict__ cur,
                                              int2* __restrict__ epack) {
    int e = blockIdx.x * 256 + threadIdx.x;
    if (e < N_EDGES) {
        int d = dst[e];
        int pos = atomicAdd(&cur[d], 1);
        epack[pos] = make_int2(src[e], __float_as_int(w[e]));
    }
}

// ---------------- Gather: hbf[v] = bf16( h0[v] + sum_e w_e * y[src_e] ) ----
__global__ __launch_bounds__(256) void k_gather(
    const unsigned short* __restrict__ ybf, const float* __restrict__ h0,
    const int* __restrict__ rowptr, const int2* __restrict__ epack,
    unsigned short* __restrict__ hbf)
{
    const int lane = threadIdx.x & 63;
    const int v = blockIdx.x * 4 + (threadIdx.x >> 6);
    const int beg = rowptr[v];
    const int end = rowptr[v + 1];
    const int f0 = lane * 2;

    float2 acc = *(const float2*)&h0[(size_t)v * HID + f0];

    for (int base = beg; base < end; base += 64) {
        int idx = base + lane;
        int2 ep = make_int2(0, 0);
        if (idx < end) ep = epack[idx];
        int cnt = min(64, end - base);
        for (int j = 0; j < cnt; ++j) {
            int s = __shfl(ep.x, j, 64);
            float wt = __int_as_float(__shfl(ep.y, j, 64));
            unsigned p = *(const unsigned*)&ybf[(size_t)s * HID + f0];
            float y0 = __builtin_bit_cast(float, p << 16);
            float y1 = __builtin_bit_cast(float, p & 0xFFFF0000u);
            acc.x += wt * y0;
            acc.y += wt * y1;
        }
    }
    unsigned r = ((unsigned)f2bf(acc.y) << 16) | (unsigned)f2bf(acc.x);
    *(unsigned*)&hbf[(size_t)v * HID + f0] = r;
}

// ---------------- GEMM2: out = hbf@Wm + bm ----------------
// M-tile 128, N-tile 128, K=128 single stage. Same wave structure as gemm1.
__global__ __launch_bounds__(256) void gemm2(
    const unsigned short* __restrict__ hbf, const unsigned short* __restrict__ Wmt,
    const float* __restrict__ bm, float* __restrict__ out)
{
    __shared__ unsigned short As[128][128];  // 32 KB
    __shared__ unsigned short Bs[128][128];  // 32 KB
    const int t = threadIdx.x;
    const int m0 = blockIdx.x * 128;
    const int n0 = blockIdx.y * 128;

    // A stage: hbf rows m0..m0+127 (256 B each = 16 f4); 2048 float4s
    const float4* ag = (const float4*)hbf;
    #pragma unroll
    for (int i = 0; i < 8; ++i) {
        int f4  = t + i * 256;
        int row = f4 >> 4;
        int node = m0 + row;
        float4 v = make_float4(0.f, 0.f, 0.f, 0.f);
        if (node < N_NODES) v = ag[(size_t)node * 16 + (f4 & 15)];
        ((float4*)&As[0][0])[f4] = v;
    }
    // B stage: Wmt rows n0..n0+127 contiguous 32 KB
    const float4* bg = (const float4*)(Wmt + (size_t)n0 * HID);
    #pragma unroll
    for (int i = 0; i < 8; ++i)
        ((float4*)&Bs[0][0])[t + i * 256] = bg[t + i * 256];
    __syncthreads();

    const int wave = t >> 6, lane = t & 63;
    const int wm = wave & 1, wn = wave >> 1;
    const int la = lane & 15, kq = lane >> 4;

    f32x4 acc[4][4];
    const f32x4 zero = {0.f, 0.f, 0.f, 0.f};
    #pragma unroll
    for (int i = 0; i < 4; ++i)
        #pragma unroll
        for (int j = 0; j < 4; ++j) acc[i][j] = zero;

    #pragma unroll
    for (int ks = 0; ks < 4; ++ks) {
        int k = ks * 32 + kq * 8;
        bf16x8 a[4], b[4];
        #pragma unroll
        for (int i = 0; i < 4; ++i)
            a[i] = *(const bf16x8*)&As[wm * 64 + i * 16 + la][k];
        #pragma unroll
        for (int j = 0; j < 4; ++j)
            b[j] = *(const bf16x8*)&Bs[wn * 64 + j * 16 + la][k];
        #pragma unroll
        for (int i = 0; i < 4; ++i)
            #pragma unroll
            for (int j = 0; j < 4; ++j)
                acc[i][j] = __builtin_amdgcn_mfma_f32_16x16x32_bf16(
                    a[i], b[j], acc[i][j], 0, 0, 0);
    }

    #pragma unroll
    for (int i = 0; i < 4; ++i) {
        int mbase = m0 + wm * 64 + i * 16 + kq * 4;
        #pragma unroll
        for (int j = 0; j < 4; ++j) {
            int n = n0 + wn * 64 + j * 16 + la;
            float b = bm[n];
            #pragma unroll
            for (int r = 0; r < 4; ++r) {
                int m = mbase + r;
                if (m < N_NODES)
                    out[(size_t)m * OUT_FEAT + n] = acc[i][j][r] + b;
            }
        }
    }
}

extern "C" void kernel_launch(void* const* d_in, const int* in_sizes, int n_in,
                              void* d_out, int out_size, void* d_ws, size_t ws_size,
                              hipStream_t stream) {
    const float* x   = (const float*)d_in[0];
    const float* w   = (const float*)d_in[1];
    const int*   src = (const int*)d_in[2];
    const int*   dst = (const int*)d_in[3];
    const float* Wn  = (const float*)d_in[4];
    const float* bn  = (const float*)d_in[5];
    const float* We  = (const float*)d_in[6];
    const float* be  = (const float*)d_in[7];
    const float* Wm  = (const float*)d_in[8];
    const float* bm  = (const float*)d_in[9];
    float* out = (float*)d_out;

    // workspace layout
    char* p = (char*)d_ws;
    float*          h0     = (float*)p;          p += (size_t)N_NODES * HID * 4;   // 25.6 MB
    unsigned short* ybf    = (unsigned short*)p; p += (size_t)N_NODES * HID * 2;   // 12.8 MB
    unsigned short* hbf    = (unsigned short*)p; p += (size_t)N_NODES * HID * 2;   // 12.8 MB
    int2*           epack  = (int2*)p;           p += (size_t)N_EDGES * 8;         // 12.8 MB
    unsigned short* Wcat_t = (unsigned short*)p; p += (size_t)256 * IN_FEAT * 2;   // 128 KB
    unsigned short* Wmt    = (unsigned short*)p; p += (size_t)OUT_FEAT * HID * 2;  // 64 KB
    int*            rowptr = (int*)p;            p += (size_t)(N_NODES + 16) * 4;
    int*            cur    = (int*)p;            p += (size_t)N_NODES * 4;
    int*            deg    = (int*)p;            p += (size_t)N_NODES * 4;
    int*            pexcl  = (int*)p;            p += (size_t)N_NODES * 4;
    int*            bsum   = (int*)p;            p += 256 * 4;
    int*            boff   = (int*)p;            p += 256 * 4;

    const int nblk_nodes = (N_NODES + 255) / 256;   // 196
    const int nblk_edges = (N_EDGES + 255) / 256;   // 6250
    const int grid_m     = (N_NODES + 127) / 128;   // 391
    dim3 blk(256);

    hipMemsetAsync(deg, 0, (size_t)N_NODES * 4, stream);
    k0_convert<<<256, blk, 0, stream>>>(Wn, We, Wm, Wcat_t, Wmt);
    k_hist <<<nblk_edges, blk, 0, stream>>>(dst, deg);
    k_scan1<<<nblk_nodes, blk, 0, stream>>>(deg, pexcl, bsum);
    k_scan2<<<1,          blk, 0, stream>>>(bsum, boff, nblk_nodes);
    k_scan3<<<nblk_nodes, blk, 0, stream>>>(pexcl, boff, rowptr, cur);
    k_fill <<<nblk_edges, blk, 0, stream>>>(src, dst, w, cur, epack);

    gemm1<<<dim3(grid_m, 2), blk, 0, stream>>>(x, Wcat_t, bn, be, h0, ybf);
    k_gather<<<N_NODES / 4, blk, 0, stream>>>(ybf, h0, rowptr, epack, hbf);
    gemm2<<<dim3(grid_m, 2), blk, 0, stream>>>(hbf, Wmt, bm, out);
}